// Round 5
// baseline (111.474 us; speedup 1.0000x reference)
//
#include <hip/hip_runtime.h>
#include <math.h>

// (b,n,h,d) = (4,8192,8,64), fp32.
// Groups: i=0: g=3,r=1,off=0,hmin=0,seg=2048  -> 8192 covered pos/b
//         i=1: g=3,r=2,off=1,hmin=3,seg=4096  -> 4096 covered pos/b (pos%2==1)
//         i=2: g=2,r=4,off=2,hmin=6,seg=8192  -> 2048 covered pos/b (pos%4==2)
#define NB 4
#define NN 8192
#define NH 8
#define ND 64
#define NPART_STRIDE 192       // per-WAVE partial: g*64 floats (max g=3)
#define N_BLOCKS_P1 1792       // 4b*(256+128+64) chunks of 32 positions
#define N_WAVES_P1  (N_BLOCKS_P1 * 4)

// R5: pass1 is a PURE MAP kernel — no LDS, no __syncthreads, no tail thread
// subset. R1-R4 showed 55-60us regardless of MLP forcing / occupancy (31-54%)
// while pass3 streams at ~18 TB/s; the differentiator is block coupling
// (barrier + 192-thread tail serializing block retirement). Per-(b,h,d) sums
// are wave-reduced in registers (shfl_xor 16/32) and written per-wave.

template<int G, int IT>
__device__ __forceinline__ void pass1_work(
    const float* __restrict__ Q, const float* __restrict__ K,
    const float* __restrict__ V, float* __restrict__ out,
    float* __restrict__ partials,
    int b, int chunk, int r, int off, int hmin, int seglen)
{
    const int tid  = threadIdx.x;   // 256 threads = 4 waves
    const int w    = tid >> 6;
    const int lane = tid & 63;
    const int sg   = lane >> 4;     // 16-lane sub-group = one position
    const int l    = lane & 15;     // lane owns d in [4l, 4l+4)

    size_t rowbase[IT];
    #pragma unroll
    for (int it = 0; it < IT; ++it) {
        const int j   = chunk * (16 * IT) + w * (4 * IT) + it * 4 + sg;
        const int seg = j >> 11;                 // 2048 dilated pos per segment
        const int td  = j & 2047;
        const int pos = seg * seglen + off + td * r;
        rowbase[it] = (((size_t)b * NN + pos) * NH + hmin) * ND + 4 * l;
    }

    float4 qv[IT][G], kv[IT][G], vv[IT][G];
    #pragma unroll
    for (int it = 0; it < IT; ++it)
        #pragma unroll
        for (int q = 0; q < G; ++q) {
            qv[it][q] = *(const float4*)(Q + rowbase[it] + q * ND);
            kv[it][q] = *(const float4*)(K + rowbase[it] + q * ND);
            vv[it][q] = *(const float4*)(V + rowbase[it] + q * ND);
        }

    float xs[G][4];
    #pragma unroll
    for (int q = 0; q < G; ++q)
        #pragma unroll
        for (int e = 0; e < 4; ++e) xs[q][e] = 0.f;

    #pragma unroll
    for (int it = 0; it < IT; ++it) {
        float sc[G][G];
        #pragma unroll
        for (int q = 0; q < G; ++q)
            #pragma unroll
            for (int k = 0; k < G; ++k)
                sc[q][k] = qv[it][q].x * kv[it][k].x + qv[it][q].y * kv[it][k].y
                         + qv[it][q].z * kv[it][k].z + qv[it][q].w * kv[it][k].w;

        // butterfly reduce across the 16 lanes of this sub-group
        #pragma unroll
        for (int o = 8; o >= 1; o >>= 1)
            #pragma unroll
            for (int q = 0; q < G; ++q)
                #pragma unroll
                for (int k = 0; k < G; ++k)
                    sc[q][k] += __shfl_xor(sc[q][k], o);

        #pragma unroll
        for (int q = 0; q < G; ++q) {
            float m = -INFINITY;
            #pragma unroll
            for (int k = 0; k < G; ++k) { sc[q][k] *= 0.125f; m = fmaxf(m, sc[q][k]); }
            float a[G]; float ssum = 0.f;
            #pragma unroll
            for (int k = 0; k < G; ++k) { a[k] = __expf(sc[q][k] - m); ssum += a[k]; }
            const float rs = 1.f / ssum;
            float xe0 = 0.f, xe1 = 0.f, xe2 = 0.f, xe3 = 0.f;
            #pragma unroll
            for (int k = 0; k < G; ++k) {
                const float aw = a[k] * rs;
                xe0 += aw * vv[it][k].x; xe1 += aw * vv[it][k].y;
                xe2 += aw * vv[it][k].z; xe3 += aw * vv[it][k].w;
            }
            // write UNNORMALIZED x to its final (disjoint) output slot
            *(float4*)(out + rowbase[it] + (size_t)q * ND) =
                make_float4(xe0, xe1, xe2, xe3);
            xs[q][0] += xe0; xs[q][1] += xe1; xs[q][2] += xe2; xs[q][3] += xe3;
        }
    }

    // ---- wave-level reduction across the 4 sub-groups (register-only) ----
    // lanes l, l+16, l+32, l+48 hold the same d-slice -> xor-reduce 16, 32.
    #pragma unroll
    for (int q = 0; q < G; ++q)
        #pragma unroll
        for (int e = 0; e < 4; ++e) {
            xs[q][e] += __shfl_xor(xs[q][e], 16);
            xs[q][e] += __shfl_xor(xs[q][e], 32);
        }

    if (lane < 16) {
        const int wid = blockIdx.x * 4 + w;
        #pragma unroll
        for (int q = 0; q < G; ++q)
            *(float4*)(partials + (size_t)wid * NPART_STRIDE + q * 64 + 4 * l) =
                make_float4(xs[q][0], xs[q][1], xs[q][2], xs[q][3]);
    }
}

__global__ __launch_bounds__(256)
void sda_pass1(const float* __restrict__ Q, const float* __restrict__ K,
               const float* __restrict__ V, float* __restrict__ out,
               float* __restrict__ partials)
{
    const int bid = blockIdx.x;
    if (bid < 1024) {                      // group 0: 4 b * 256 chunks
        const int b = bid >> 8, chunk = bid & 255;
        pass1_work<3, 2>(Q, K, V, out, partials, b, chunk, 1, 0, 0, 2048);
    } else if (bid < 1536) {               // group 1: 4 b * 128 chunks
        const int loc = bid - 1024;
        const int b = loc >> 7, chunk = loc & 127;
        pass1_work<3, 2>(Q, K, V, out, partials, b, chunk, 2, 1, 3, 4096);
    } else {                               // group 2: 4 b * 64 chunks
        const int loc = bid - 1536;
        const int b = loc >> 6, chunk = loc & 63;
        pass1_work<2, 2>(Q, K, V, out, partials, b, chunk, 4, 2, 6, 8192);
    }
}

__global__ __launch_bounds__(256)
void sda_pass2(const float* __restrict__ partials, float* __restrict__ inv)
{
    const int bh = blockIdx.x;            // 32 blocks = b*8+h
    const int b  = bh >> 3;
    const int h  = bh & 7;
    const int d    = threadIdx.x & 63;
    const int part = threadIdx.x >> 6;    // 4-way split of the wave list
    int qi, wstart, cnt;                  // wave-id range covering (b, group)
    if (h < 3)      { qi = h;     wstart = (b * 256) * 4;        cnt = 1024; }
    else if (h < 6) { qi = h - 3; wstart = (1024 + b * 128) * 4; cnt = 512;  }
    else            { qi = h - 6; wstart = (1536 + b * 64) * 4;  cnt = 256;  }
    float s = 0.f;
    for (int c = part; c < cnt; c += 4)
        s += partials[(size_t)(wstart + c) * NPART_STRIDE + qi * 64 + d];
    __shared__ float sred[4][64];
    sred[part][d] = s;
    __syncthreads();
    if (part == 0) {
        const float tot = sred[0][d] + sred[1][d] + sred[2][d] + sred[3][d];
        inv[bh * 64 + d] = 1.f / (3.f * (tot + 1e-8f));
    }
}

__global__ __launch_bounds__(256)
void sda_pass3(float* __restrict__ out, const float* __restrict__ inv)
{
    const int total4 = NB * NN * NH * ND / 4;   // 4,194,304 float4s
    for (int idx = blockIdx.x * 256 + threadIdx.x; idx < total4;
         idx += gridDim.x * 256) {
        const int d4  = idx & 15;
        const int rem = idx >> 4;
        const int h   = rem & 7;
        const int pos = (rem >> 3) & 8191;
        const int b   = rem >> 16;
        const bool cov = (h < 3) || ((h < 6) ? ((pos & 1) == 1) : ((pos & 3) == 2));
        float4 o;
        if (cov) {
            const float4 v = ((const float4*)out)[idx];
            const float4 f = ((const float4*)inv)[b * 128 + h * 16 + d4];
            o = make_float4(v.x * f.x, v.y * f.y, v.z * f.z, v.w * f.w);
        } else {
            o = make_float4(0.f, 0.f, 0.f, 0.f);
        }
        ((float4*)out)[idx] = o;
    }
}

extern "C" void kernel_launch(void* const* d_in, const int* in_sizes, int n_in,
                              void* d_out, int out_size, void* d_ws, size_t ws_size,
                              hipStream_t stream)
{
    const float* Q = (const float*)d_in[0];
    const float* K = (const float*)d_in[1];
    const float* V = (const float*)d_in[2];
    float* out      = (float*)d_out;
    float* partials = (float*)d_ws;                           // 7168*192*4 B ≈ 5.5 MB
    float* inv      = partials + (size_t)N_WAVES_P1 * NPART_STRIDE;

    hipLaunchKernelGGL(sda_pass1, dim3(N_BLOCKS_P1), dim3(256), 0, stream,
                       Q, K, V, out, partials);
    hipLaunchKernelGGL(sda_pass2, dim3(32), dim3(256), 0, stream, partials, inv);
    hipLaunchKernelGGL(sda_pass3, dim3(2048), dim3(256), 0, stream, out, inv);
}

// Round 6
// 54.284 us; speedup vs baseline: 2.0535x; 2.0535x over previous
//
#include <hip/hip_runtime.h>
#include <math.h>

// (b,n,h,d) = (4,8192,8,64), fp32.
// Groups: i=0: g=3,r=1,off=0,hmin=0,seg=2048  -> 8192 covered pos/b
//         i=1: g=3,r=2,off=1,hmin=3,seg=4096  -> 4096 covered pos/b (pos%2==1)
//         i=2: g=4... no: g=2,r=4,off=2,hmin=6,seg=8192 -> 2048 covered pos/b (pos%4==2)
#define NB 4
#define NN 8192
#define NH 8
#define ND 64
#define NPART_STRIDE 192       // per-WAVE partial: g*64 floats (max g=3)
#define N_BLOCKS_P1 1792       // 4b*(256+128+64) chunks of 32 positions
#define N_WAVES_P1  (N_BLOCKS_P1 * 4)

// pass1: PURE MAP kernel — no LDS, no __syncthreads, no tail (R5: 56->41us).
// pass2 split two-level (R5 post-mortem: 32-block pass2 = 0.8% occupancy, 64us).

template<int G, int IT>
__device__ __forceinline__ void pass1_work(
    const float* __restrict__ Q, const float* __restrict__ K,
    const float* __restrict__ V, float* __restrict__ out,
    float* __restrict__ partials,
    int b, int chunk, int r, int off, int hmin, int seglen)
{
    const int tid  = threadIdx.x;   // 256 threads = 4 waves
    const int w    = tid >> 6;
    const int lane = tid & 63;
    const int sg   = lane >> 4;     // 16-lane sub-group = one position
    const int l    = lane & 15;     // lane owns d in [4l, 4l+4)

    size_t rowbase[IT];
    #pragma unroll
    for (int it = 0; it < IT; ++it) {
        const int j   = chunk * (16 * IT) + w * (4 * IT) + it * 4 + sg;
        const int seg = j >> 11;                 // 2048 dilated pos per segment
        const int td  = j & 2047;
        const int pos = seg * seglen + off + td * r;
        rowbase[it] = (((size_t)b * NN + pos) * NH + hmin) * ND + 4 * l;
    }

    float4 qv[IT][G], kv[IT][G], vv[IT][G];
    #pragma unroll
    for (int it = 0; it < IT; ++it)
        #pragma unroll
        for (int q = 0; q < G; ++q) {
            qv[it][q] = *(const float4*)(Q + rowbase[it] + q * ND);
            kv[it][q] = *(const float4*)(K + rowbase[it] + q * ND);
            vv[it][q] = *(const float4*)(V + rowbase[it] + q * ND);
        }

    float xs[G][4];
    #pragma unroll
    for (int q = 0; q < G; ++q)
        #pragma unroll
        for (int e = 0; e < 4; ++e) xs[q][e] = 0.f;

    #pragma unroll
    for (int it = 0; it < IT; ++it) {
        float sc[G][G];
        #pragma unroll
        for (int q = 0; q < G; ++q)
            #pragma unroll
            for (int k = 0; k < G; ++k)
                sc[q][k] = qv[it][q].x * kv[it][k].x + qv[it][q].y * kv[it][k].y
                         + qv[it][q].z * kv[it][k].z + qv[it][q].w * kv[it][k].w;

        // butterfly reduce across the 16 lanes of this sub-group
        #pragma unroll
        for (int o = 8; o >= 1; o >>= 1)
            #pragma unroll
            for (int q = 0; q < G; ++q)
                #pragma unroll
                for (int k = 0; k < G; ++k)
                    sc[q][k] += __shfl_xor(sc[q][k], o);

        #pragma unroll
        for (int q = 0; q < G; ++q) {
            float m = -INFINITY;
            #pragma unroll
            for (int k = 0; k < G; ++k) { sc[q][k] *= 0.125f; m = fmaxf(m, sc[q][k]); }
            float a[G]; float ssum = 0.f;
            #pragma unroll
            for (int k = 0; k < G; ++k) { a[k] = __expf(sc[q][k] - m); ssum += a[k]; }
            const float rs = 1.f / ssum;
            float xe0 = 0.f, xe1 = 0.f, xe2 = 0.f, xe3 = 0.f;
            #pragma unroll
            for (int k = 0; k < G; ++k) {
                const float aw = a[k] * rs;
                xe0 += aw * vv[it][k].x; xe1 += aw * vv[it][k].y;
                xe2 += aw * vv[it][k].z; xe3 += aw * vv[it][k].w;
            }
            // write UNNORMALIZED x to its final (disjoint) output slot
            *(float4*)(out + rowbase[it] + (size_t)q * ND) =
                make_float4(xe0, xe1, xe2, xe3);
            xs[q][0] += xe0; xs[q][1] += xe1; xs[q][2] += xe2; xs[q][3] += xe3;
        }
    }

    // ---- wave-level reduction across the 4 sub-groups (register-only) ----
    #pragma unroll
    for (int q = 0; q < G; ++q)
        #pragma unroll
        for (int e = 0; e < 4; ++e) {
            xs[q][e] += __shfl_xor(xs[q][e], 16);
            xs[q][e] += __shfl_xor(xs[q][e], 32);
        }

    if (lane < 16) {
        const int wid = blockIdx.x * 4 + w;
        #pragma unroll
        for (int q = 0; q < G; ++q)
            *(float4*)(partials + (size_t)wid * NPART_STRIDE + q * 64 + 4 * l) =
                make_float4(xs[q][0], xs[q][1], xs[q][2], xs[q][3]);
    }
}

__global__ __launch_bounds__(256)
void sda_pass1(const float* __restrict__ Q, const float* __restrict__ K,
               const float* __restrict__ V, float* __restrict__ out,
               float* __restrict__ partials)
{
    const int bid = blockIdx.x;
    if (bid < 1024) {                      // group 0: 4 b * 256 chunks
        const int b = bid >> 8, chunk = bid & 255;
        pass1_work<3, 2>(Q, K, V, out, partials, b, chunk, 1, 0, 0, 2048);
    } else if (bid < 1536) {               // group 1: 4 b * 128 chunks
        const int loc = bid - 1024;
        const int b = loc >> 7, chunk = loc & 127;
        pass1_work<3, 2>(Q, K, V, out, partials, b, chunk, 2, 1, 3, 4096);
    } else {                               // group 2: 4 b * 64 chunks
        const int loc = bid - 1536;
        const int b = loc >> 6, chunk = loc & 63;
        pass1_work<2, 2>(Q, K, V, out, partials, b, chunk, 4, 2, 6, 8192);
    }
}

// pass2a: 256 blocks = (bh 0..31) x (slice 0..7). Each reduces its slice of
// the wave-partial list for that (b, head) with coalesced reads.
__global__ __launch_bounds__(256)
void sda_pass2a(const float* __restrict__ partials, float* __restrict__ partial2)
{
    const int bid   = blockIdx.x;
    const int bh    = bid >> 3;
    const int slice = bid & 7;
    const int b     = bh >> 3;
    const int h     = bh & 7;
    const int d     = threadIdx.x & 63;
    const int part  = threadIdx.x >> 6;   // 4-way split of the slice
    int qi, wstart, cnt;
    if (h < 3)      { qi = h;     wstart = b * 1024;       cnt = 1024; }
    else if (h < 6) { qi = h - 3; wstart = 4096 + b * 512; cnt = 512;  }
    else            { qi = h - 6; wstart = 6144 + b * 256; cnt = 256;  }
    const int len = cnt >> 3;             // 128 / 64 / 32
    const int c0  = wstart + slice * len;
    float s = 0.f;
    #pragma unroll 4
    for (int c = part; c < len; c += 4)
        s += partials[(size_t)(c0 + c) * NPART_STRIDE + qi * 64 + d];
    __shared__ float sred[4][64];
    sred[part][d] = s;
    __syncthreads();
    if (part == 0)
        partial2[(size_t)bid * 64 + d] = sred[0][d] + sred[1][d] + sred[2][d] + sred[3][d];
}

// pass2b: finish 8 slice-partials per (b,h,d) -> inv
__global__ __launch_bounds__(256)
void sda_pass2b(const float* __restrict__ partial2, float* __restrict__ inv)
{
    const int t = blockIdx.x * 256 + threadIdx.x;   // 2048 = bh*64 + d
    if (t >= NB * NH * ND) return;
    const int bh = t >> 6;
    const int d  = t & 63;
    float s = 0.f;
    #pragma unroll
    for (int sl = 0; sl < 8; ++sl)
        s += partial2[(size_t)(bh * 8 + sl) * 64 + d];
    inv[t] = 1.f / (3.f * (s + 1e-8f));
}

__global__ __launch_bounds__(256)
void sda_pass3(float* __restrict__ out, const float* __restrict__ inv)
{
    const int total4 = NB * NN * NH * ND / 4;   // 4,194,304 float4s
    for (int idx = blockIdx.x * 256 + threadIdx.x; idx < total4;
         idx += gridDim.x * 256) {
        const int d4  = idx & 15;
        const int rem = idx >> 4;
        const int h   = rem & 7;
        const int pos = (rem >> 3) & 8191;
        const int b   = rem >> 16;
        const bool cov = (h < 3) || ((h < 6) ? ((pos & 1) == 1) : ((pos & 3) == 2));
        float4 o;
        if (cov) {
            const float4 v = ((const float4*)out)[idx];
            const float4 f = ((const float4*)inv)[b * 128 + h * 16 + d4];
            o = make_float4(v.x * f.x, v.y * f.y, v.z * f.z, v.w * f.w);
        } else {
            o = make_float4(0.f, 0.f, 0.f, 0.f);
        }
        ((float4*)out)[idx] = o;
    }
}

extern "C" void kernel_launch(void* const* d_in, const int* in_sizes, int n_in,
                              void* d_out, int out_size, void* d_ws, size_t ws_size,
                              hipStream_t stream)
{
    const float* Q = (const float*)d_in[0];
    const float* K = (const float*)d_in[1];
    const float* V = (const float*)d_in[2];
    float* out      = (float*)d_out;
    float* partials = (float*)d_ws;                            // 7168*192*4 ≈ 5.5 MB
    float* partial2 = partials + (size_t)N_WAVES_P1 * NPART_STRIDE; // +16384 floats
    float* inv      = partial2 + 256 * 64;                     // +2048 floats

    hipLaunchKernelGGL(sda_pass1,  dim3(N_BLOCKS_P1), dim3(256), 0, stream,
                       Q, K, V, out, partials);
    hipLaunchKernelGGL(sda_pass2a, dim3(256), dim3(256), 0, stream, partials, partial2);
    hipLaunchKernelGGL(sda_pass2b, dim3(8),   dim3(256), 0, stream, partial2, inv);
    hipLaunchKernelGGL(sda_pass3,  dim3(2048), dim3(256), 0, stream, out, inv);
}

// Round 7
// 53.264 us; speedup vs baseline: 2.0929x; 1.0192x over previous
//
#include <hip/hip_runtime.h>
#include <math.h>

// (b,n,h,d) = (4,8192,8,64), fp32.
// Groups: i=0: g=3,r=1,off=0,hmin=0,seg=2048  -> 8192 covered pos/b
//         i=1: g=3,r=2,off=1,hmin=3,seg=4096  -> 4096 covered pos/b (pos%2==1)
//         i=2: g=2,r=4,off=2,hmin=6,seg=8192  -> 2048 covered pos/b (pos%4==2)
#define NB 4
#define NN 8192
#define NH 8
#define ND 64
#define NPART_STRIDE 192        // per-BLOCK partial: g*64 floats (max g=3)
#define N_BLOCKS_P1 3584        // 4b*(512+256+128) blocks of 16 positions

// R7: pass1 stages Q/K/V via __builtin_amdgcn_global_load_lds (async DMA,
// zero VGPR pressure). R2-R6: allocator capped in-flight register loads at
// ~2-3/wave -> 1.9-2.4 TB/s latency-bound. Here each wave holds 9 x 1KB DMAs
// in flight (vmcnt-tracked), vmcnt(G) staged wait overlaps V with softmax.

__device__ __forceinline__ void gload_lds16(const float* g, float* l) {
    __builtin_amdgcn_global_load_lds(
        (__attribute__((address_space(1))) void*)const_cast<float*>(g),
        (__attribute__((address_space(3))) void*)l, 16, 0, 0);
}

template<int G>
__device__ __forceinline__ void pass1_work(
    const float* __restrict__ Q, const float* __restrict__ K,
    const float* __restrict__ V, float* __restrict__ out,
    float* __restrict__ partials,
    float (*stage)[9][256], float (*red)[3][64],
    int b, int chunk, int r, int off, int hmin, int seglen)
{
    const int tid  = threadIdx.x;   // 256 threads = 4 waves
    const int w    = tid >> 6;
    const int lane = tid & 63;
    const int sg   = lane >> 4;     // 16-lane sub-group = one position
    const int l    = lane & 15;     // lane owns d in [4l, 4l+4)

    const int j   = chunk * 16 + w * 4 + sg;
    const int pos = (j >> 11) * seglen + off + (j & 2047) * r;
    const size_t rowbase = (((size_t)b * NN + pos) * NH + hmin) * ND + 4 * l;

    // ---- issue 3G async 1KB DMAs: global (per-lane addr) -> LDS (linear) ----
    #pragma unroll
    for (int q = 0; q < G; ++q) gload_lds16(Q + rowbase + q * ND, &stage[w][q][0]);
    #pragma unroll
    for (int q = 0; q < G; ++q) gload_lds16(K + rowbase + q * ND, &stage[w][3 + q][0]);
    #pragma unroll
    for (int q = 0; q < G; ++q) gload_lds16(V + rowbase + q * ND, &stage[w][6 + q][0]);

    // ---- wait for Q,K only; the G V-loads stay in flight under softmax ----
    asm volatile("s_waitcnt vmcnt(%0)" :: "n"(G) : "memory");
    __builtin_amdgcn_sched_barrier(0);

    float4 qv[G], kv[G];
    #pragma unroll
    for (int q = 0; q < G; ++q) {
        qv[q] = *(const float4*)&stage[w][q][4 * lane];
        kv[q] = *(const float4*)&stage[w][3 + q][4 * lane];
    }

    float sc[G][G];
    #pragma unroll
    for (int q = 0; q < G; ++q)
        #pragma unroll
        for (int k = 0; k < G; ++k)
            sc[q][k] = qv[q].x * kv[k].x + qv[q].y * kv[k].y
                     + qv[q].z * kv[k].z + qv[q].w * kv[k].w;

    // butterfly reduce across the 16 lanes of this sub-group
    #pragma unroll
    for (int o = 8; o >= 1; o >>= 1)
        #pragma unroll
        for (int q = 0; q < G; ++q)
            #pragma unroll
            for (int k = 0; k < G; ++k)
                sc[q][k] += __shfl_xor(sc[q][k], o);

    // per-lane (redundant) softmax over k
    #pragma unroll
    for (int q = 0; q < G; ++q) {
        float m = -INFINITY;
        #pragma unroll
        for (int k = 0; k < G; ++k) { sc[q][k] *= 0.125f; m = fmaxf(m, sc[q][k]); }
        float ssum = 0.f;
        #pragma unroll
        for (int k = 0; k < G; ++k) { sc[q][k] = __expf(sc[q][k] - m); ssum += sc[q][k]; }
        const float rs = 1.f / ssum;
        #pragma unroll
        for (int k = 0; k < G; ++k) sc[q][k] *= rs;
    }

    // ---- drain V DMAs, then PV + store ----
    asm volatile("s_waitcnt vmcnt(0)" ::: "memory");
    __builtin_amdgcn_sched_barrier(0);

    float4 vv[G];
    #pragma unroll
    for (int q = 0; q < G; ++q)
        vv[q] = *(const float4*)&stage[w][6 + q][4 * lane];

    float xs[G][4];
    #pragma unroll
    for (int q = 0; q < G; ++q) {
        float xe0 = 0.f, xe1 = 0.f, xe2 = 0.f, xe3 = 0.f;
        #pragma unroll
        for (int k = 0; k < G; ++k) {
            const float aw = sc[q][k];
            xe0 += aw * vv[k].x; xe1 += aw * vv[k].y;
            xe2 += aw * vv[k].z; xe3 += aw * vv[k].w;
        }
        *(float4*)(out + rowbase + (size_t)q * ND) = make_float4(xe0, xe1, xe2, xe3);
        xs[q][0] = xe0; xs[q][1] = xe1; xs[q][2] = xe2; xs[q][3] = xe3;
    }

    // wave-level reduction across the 4 sub-groups (register-only)
    #pragma unroll
    for (int q = 0; q < G; ++q)
        #pragma unroll
        for (int e = 0; e < 4; ++e) {
            xs[q][e] += __shfl_xor(xs[q][e], 16);
            xs[q][e] += __shfl_xor(xs[q][e], 32);
        }

    if (lane < 16)
        #pragma unroll
        for (int q = 0; q < G; ++q)
            *(float4*)&red[w][q][4 * l] = make_float4(xs[q][0], xs[q][1], xs[q][2], xs[q][3]);
    __syncthreads();

    if (tid < G * 64) {
        const int q = tid >> 6;
        const int d = tid & 63;
        partials[(size_t)blockIdx.x * NPART_STRIDE + q * 64 + d] =
            red[0][q][d] + red[1][q][d] + red[2][q][d] + red[3][q][d];
    }
}

__global__ __launch_bounds__(256)
void sda_pass1(const float* __restrict__ Q, const float* __restrict__ K,
               const float* __restrict__ V, float* __restrict__ out,
               float* __restrict__ partials)
{
    __shared__ float stage[4][9][256];   // 36 KB: 4 waves x 9 slots x 1KB
    __shared__ float red[4][3][64];      // 3 KB
    const int bid = blockIdx.x;
    if (bid < 2048) {                      // group 0: 4 b * 512 blocks
        const int b = bid >> 9, chunk = bid & 511;
        pass1_work<3>(Q, K, V, out, partials, stage, red, b, chunk, 1, 0, 0, 2048);
    } else if (bid < 3072) {               // group 1: 4 b * 256 blocks
        const int loc = bid - 2048;
        const int b = loc >> 8, chunk = loc & 255;
        pass1_work<3>(Q, K, V, out, partials, stage, red, b, chunk, 2, 1, 3, 4096);
    } else {                               // group 2: 4 b * 128 blocks
        const int loc = bid - 3072;
        const int b = loc >> 7, chunk = loc & 127;
        pass1_work<2>(Q, K, V, out, partials, stage, red, b, chunk, 4, 2, 6, 8192);
    }
}

// pass2a: 256 blocks = (bh 0..31) x (slice 0..7); coalesced block-partial reduce.
__global__ __launch_bounds__(256)
void sda_pass2a(const float* __restrict__ partials, float* __restrict__ partial2)
{
    const int bid   = blockIdx.x;
    const int bh    = bid >> 3;
    const int slice = bid & 7;
    const int b     = bh >> 3;
    const int h     = bh & 7;
    const int d     = threadIdx.x & 63;
    const int part  = threadIdx.x >> 6;   // 4-way split of the slice
    int qi, bstart, cnt;
    if (h < 3)      { qi = h;     bstart = b * 512;        cnt = 512; }
    else if (h < 6) { qi = h - 3; bstart = 2048 + b * 256; cnt = 256; }
    else            { qi = h - 6; bstart = 3072 + b * 128; cnt = 128; }
    const int len = cnt >> 3;             // 64 / 32 / 16
    const int c0  = bstart + slice * len;
    float s = 0.f;
    #pragma unroll 4
    for (int c = part; c < len; c += 4)
        s += partials[(size_t)(c0 + c) * NPART_STRIDE + qi * 64 + d];
    __shared__ float sred[4][64];
    sred[part][d] = s;
    __syncthreads();
    if (part == 0)
        partial2[(size_t)bid * 64 + d] = sred[0][d] + sred[1][d] + sred[2][d] + sred[3][d];
}

// pass2b: finish 8 slice-partials per (b,h,d) -> inv
__global__ __launch_bounds__(256)
void sda_pass2b(const float* __restrict__ partial2, float* __restrict__ inv)
{
    const int t = blockIdx.x * 256 + threadIdx.x;   // 2048 = bh*64 + d
    if (t >= NB * NH * ND) return;
    const int bh = t >> 6;
    const int d  = t & 63;
    float s = 0.f;
    #pragma unroll
    for (int sl = 0; sl < 8; ++sl)
        s += partial2[(size_t)(bh * 8 + sl) * 64 + d];
    inv[t] = 1.f / (3.f * (s + 1e-8f));
}

__global__ __launch_bounds__(256)
void sda_pass3(float* __restrict__ out, const float* __restrict__ inv)
{
    const int total4 = NB * NN * NH * ND / 4;   // 4,194,304 float4s
    for (int idx = blockIdx.x * 256 + threadIdx.x; idx < total4;
         idx += gridDim.x * 256) {
        const int d4  = idx & 15;
        const int rem = idx >> 4;
        const int h   = rem & 7;
        const int pos = (rem >> 3) & 8191;
        const int b   = rem >> 16;
        const bool cov = (h < 3) || ((h < 6) ? ((pos & 1) == 1) : ((pos & 3) == 2));
        float4 o;
        if (cov) {
            const float4 v = ((const float4*)out)[idx];
            const float4 f = ((const float4*)inv)[b * 128 + h * 16 + d4];
            o = make_float4(v.x * f.x, v.y * f.y, v.z * f.z, v.w * f.w);
        } else {
            o = make_float4(0.f, 0.f, 0.f, 0.f);
        }
        ((float4*)out)[idx] = o;
    }
}

extern "C" void kernel_launch(void* const* d_in, const int* in_sizes, int n_in,
                              void* d_out, int out_size, void* d_ws, size_t ws_size,
                              hipStream_t stream)
{
    const float* Q = (const float*)d_in[0];
    const float* K = (const float*)d_in[1];
    const float* V = (const float*)d_in[2];
    float* out      = (float*)d_out;
    float* partials = (float*)d_ws;                              // 3584*192*4 ≈ 2.75 MB
    float* partial2 = partials + (size_t)N_BLOCKS_P1 * NPART_STRIDE; // +16384 floats
    float* inv      = partial2 + 256 * 64;                       // +2048 floats

    hipLaunchKernelGGL(sda_pass1,  dim3(N_BLOCKS_P1), dim3(256), 0, stream,
                       Q, K, V, out, partials);
    hipLaunchKernelGGL(sda_pass2a, dim3(256), dim3(256), 0, stream, partials, partial2);
    hipLaunchKernelGGL(sda_pass2b, dim3(8),   dim3(256), 0, stream, partial2, inv);
    hipLaunchKernelGGL(sda_pass3,  dim3(2048), dim3(256), 0, stream, out, inv);
}